// Round 17
// baseline (30.517 us; speedup 1.0000x reference)
//
#include <hip/hip_runtime.h>

#define SEQ   2048
#define EMB   128
#define NH    16
#define NB    2
#define NBH   (NB * NH)      // 32
#define QB    128            // q rows per block
#define NQB   (SEQ / QB)     // 16
#define K1_THREADS 512

typedef _Float16 half_t;
typedef _Float16 half4  __attribute__((ext_vector_type(4)));
typedef __fp16   fp16x2 __attribute__((ext_vector_type(2)));  // cvt_pkrtz return type
typedef float    floatx16 __attribute__((ext_vector_type(16)));

// ws carve (exactly 2 MiB, the proven-available size):
//   zrow : half4-grain, [bh][hi][t]  (32*2*2048 half4 = 1 MiB) @ 0
//   zT   : half grain,  [bh][d][t]   (32*8*2048 half  = 1 MiB) @ 1 MiB
#define ZROW_H4_PER_BH (2 * SEQ)
#define ZT_H_PER_BH    (8 * SEQ)

// k1 LDS: zqk [2][2048] half4 @0 (32768 B); zT 9 rows pitch 4112 @32768
// (pitch 4112 B: 16B-aligned rows, 4-bank shift/row -> <=2-way conflicts);
// red float[4352] aliases zqk after the final barrier.
#define ZT_OFF     32768
#define ZT_PITCH   4112
#define SMEM_BYTES (ZT_OFF + 9 * ZT_PITCH)   // 69776 -> 2 blocks/CU

// Kernel 0: z = cos(x+theta) as f16, computed ONCE (vs 32x redundant
// per-block staging cos in R8-R15). Writes both layouts k1 needs.
__global__ __launch_bounds__(512)
void zprep_kernel(const float* __restrict__ x, const float* __restrict__ theta,
                  half_t* __restrict__ zrow, half_t* __restrict__ zT)
{
    const int bh = blockIdx.x >> 2;                       // 0..31
    const int t  = ((blockIdx.x & 3) << 9) | threadIdx.x; // 0..2047
    const int b  = bh >> 4;
    const int h  = bh & (NH - 1);

    float th[8];
#pragma unroll
    for (int d = 0; d < 8; ++d) th[d] = theta[d];

    const float4* xp = (const float4*)x + (size_t)(b * SEQ + t) * (EMB / 4) + h * 2;
    float4 lo  = xp[0];
    float4 hi4 = xp[1];
    half4 zl, zh;
    zl[0] = (half_t)__cosf(lo.x  + th[0]);
    zl[1] = (half_t)__cosf(lo.y  + th[1]);
    zl[2] = (half_t)__cosf(lo.z  + th[2]);
    zl[3] = (half_t)__cosf(lo.w  + th[3]);
    zh[0] = (half_t)__cosf(hi4.x + th[4]);
    zh[1] = (half_t)__cosf(hi4.y + th[5]);
    zh[2] = (half_t)__cosf(hi4.z + th[6]);
    zh[3] = (half_t)__cosf(hi4.w + th[7]);

    half4* zr = (half4*)zrow + (size_t)bh * ZROW_H4_PER_BH;
    zr[t]       = zl;          // [hi=0][t]
    zr[SEQ + t] = zh;          // [hi=1][t]

    half_t* zt = zT + (size_t)bh * ZT_H_PER_BH;
    zt[0 * SEQ + t] = zl[0];
    zt[1 * SEQ + t] = zl[1];
    zt[2 * SEQ + t] = zl[2];
    zt[3 * SEQ + t] = zl[3];
    zt[4 * SEQ + t] = zh[0];
    zt[5 * SEQ + t] = zh[1];
    zt[6 * SEQ + t] = zh[2];
    zt[7 * SEQ + t] = zh[3];
}

// Kernel 1: MFMA flash attention, block = (bh, q-tile), FULL t-range.
// R10-proven inner loop (intrinsic 32x32x8, swapped QK^T, ones-column l).
// Staging = pure vector copies; normalization in-kernel (l via shfl from
// D col 8); writes normalized Xn f16 into pD = d_out alias. Global row
// index INCLUDES the batch term (b*SEQ + qq) -- R16's bug was dropping it.
// Row r's Xn occupies halves [r*256, r*256+128) = first half of out row
// r's bytes -> combine reads only rows it later overwrites: race-free.
__global__ __launch_bounds__(K1_THREADS)
void qattn_mfma_kernel(const half_t* __restrict__ zrow,
                       const half_t* __restrict__ zT,
                       half_t* __restrict__ pD)
{
    __shared__ __align__(16) char smem[SMEM_BYTES];

    const int tid = threadIdx.x;
    const int qb  = blockIdx.x & (NQB - 1);
    const int bh  = blockIdx.x >> 4;
    const int b   = bh >> 4;
    const int h   = bh & (NH - 1);

    // ---- stage: zqk copy (32 KB), zT pitched copy (8 rows), ones row ----
    half4* zqk = (half4*)smem;
    const half4* zr = (const half4*)zrow + (size_t)bh * ZROW_H4_PER_BH;
#pragma unroll
    for (int i = 0; i < 4; ++i) {
        const int idx = tid + i * K1_THREADS;            // 0..2047 16B chunks
        *(float4*)&zqk[idx * 2] = *(const float4*)&zr[idx * 2];
    }
    const half_t* ztg = zT + (size_t)bh * ZT_H_PER_BH;
#pragma unroll
    for (int i = 0; i < 4; ++i) {
        const int idx = tid + i * K1_THREADS;            // 0..2047
        const int row = idx >> 8;                        // 8 rows
        const int cc  = idx & 255;                       // 256 x 16B per row
        *(float4*)(smem + ZT_OFF + row * ZT_PITCH + cc * 16) =
            *(const float4*)&ztg[row * SEQ + cc * 8];
    }
    {   // ones row (d=8) -> row-sum l falls out of the PV MFMA
        half4 one4;
        one4[0] = one4[1] = one4[2] = one4[3] = (half_t)1.0f;
        *(half4*)(smem + ZT_OFF + 8 * ZT_PITCH + tid * 8) = one4;
    }

    const int lane = tid & 63;
    const int wid  = tid >> 6;      // 0..7
    const int g    = wid & 3;       // q-tile (32 q) within block
    const int c    = wid >> 2;      // t-half (0: t<1024, 1: t>=1024)
    const int ln   = lane & 31;
    const int hi   = lane >> 5;

    // Q-frag from precomputed z (8B load), fold C = log2(e)/sqrt(8) in f16
    const float C = 0.35355339059327373f * 1.4426950408889634f;
    const int q = qb * QB + g * 32 + ln;
    half4 qf = zr[hi * SEQ + q];
    qf *= (half_t)C;

    __syncthreads();

    const half4* kp  = zqk + hi * SEQ + ln;              // kp[t0] = z[t0+ln][4hi..]
    const int    dcl = (ln < 8) ? ln : 8;                // lanes d>8 read ones row;
    const half4* vp  = (const half4*)(smem + ZT_OFF + dcl * ZT_PITCH + hi * 8);
                                                         // their D cols are never read
    floatx16 acc = {};
    const floatx16 zero16 = {};
    const int tb = c * (SEQ / 2);

#pragma unroll 1
    for (int tt = 0; tt < SEQ / 2; tt += 32) {
        const int t0 = tb + tt;
        half4 kf = kp[t0];
        // s[t_local, q]: q = ln, t_local = (r&3)+8*(r>>2)+4*hi  (scaled scores)
        floatx16 s = __builtin_amdgcn_mfma_f32_32x32x8f16(kf, qf, zero16, 0, 0, 0);
        float p[16];
#pragma unroll
        for (int r = 0; r < 16; ++r) p[r] = __builtin_amdgcn_exp2f(s[r]);
#pragma unroll
        for (int w = 0; w < 4; ++w) {
            // PV A-frag for t-window w = regs 4w..4w+3
            union { half4 h4; fp16x2 f2[2]; } u;
            u.f2[0] = __builtin_amdgcn_cvt_pkrtz(p[4 * w + 0], p[4 * w + 1]);
            u.f2[1] = __builtin_amdgcn_cvt_pkrtz(p[4 * w + 2], p[4 * w + 3]);
            half4 vf = vp[(t0 >> 2) + 2 * w];
            acc = __builtin_amdgcn_mfma_f32_32x32x8f16(u.h4, vf, acc, 0, 0, 0);
        }
    }

    // ---- combine t-halves (red aliases zqk), normalize, write Xn f16 ----
    __syncthreads();                        // all zqk/zT reads done
    float* red = (float*)smem;
    const int slot = (g * 64 + lane) * 17;  // stride 17: conflict-free
    if (c == 1) {
#pragma unroll
        for (int r = 0; r < 16; ++r) red[slot + r] = acc[r];
    }
    __syncthreads();
    if (c == 0) {
#pragma unroll
        for (int r = 0; r < 16; ++r) acc[r] += red[slot + r];

        const int q0 = qb * QB + g * 32 + 4 * hi;
#pragma unroll
        for (int r = 0; r < 16; ++r) {
            // row-sum l sits in D col 8 -> lane (8 | hi*32), same reg
            float lsum = __shfl(acc[r], 8 | (lane & 32), 64);
            acc[r] *= __builtin_amdgcn_rcpf(lsum);
        }
        if (ln < 8) {
#pragma unroll
            for (int r = 0; r < 16; ++r) {
                const int qq = q0 + (r & 3) + 8 * (r >> 2);
                pD[(size_t)(b * SEQ + qq) * 256 + h * 8 + ln] = (half_t)acc[r];
            }
        }
    }
}

// Kernel 2 (MFMA): Xn (already normalized f16) + W f16 -> out = Xn W^T.
#define K2_ROWS    32
#define K2_THREADS 256
#define XW_PITCH   132

__global__ __launch_bounds__(K2_THREADS)
void combine_mfma_kernel(const half_t* pD,
                         const float* __restrict__ W,
                         float* out)
{
    __shared__ half_t Ws[128 * XW_PITCH];      // [e][k] f16, 33792 B
    __shared__ half_t Xs[K2_ROWS * XW_PITCH];  // [r][k] f16, 8448 B

    const int tid   = threadIdx.x;
    const int rbase = blockIdx.x * K2_ROWS;

    // ---- stage W as f16 ----
#pragma unroll
    for (int it = 0; it < 16; ++it) {
        const int idx = tid + it * K2_THREADS;   // 0..4095 float4s
        const int e   = idx >> 5;
        const int k4  = idx & 31;
        float4 w = ((const float4*)W)[idx];
        union { half4 h4; fp16x2 f2[2]; } u;
        u.f2[0] = __builtin_amdgcn_cvt_pkrtz(w.x, w.y);
        u.f2[1] = __builtin_amdgcn_cvt_pkrtz(w.z, w.w);
        *(half4*)&Ws[e * XW_PITCH + 4 * k4] = u.h4;
    }
    // ---- stage Xn: straight f16 copy (pitch 256 halves in pD) ----
#pragma unroll
    for (int it = 0; it < 4; ++it) {
        const int idx = tid + it * K2_THREADS;   // 0..1023 8B chunks
        const int r   = idx >> 5;                // 32 chunks per row
        const int cc  = idx & 31;
        *(half4*)&Xs[r * XW_PITCH + cc * 4] =
            *(const half4*)&pD[(size_t)(rbase + r) * 256 + cc * 4];
    }
    __syncthreads();

    const int lane = tid & 63;
    const int wv   = tid >> 6;     // 0..3 -> e-tile
    const int ln   = lane & 31;
    const int hi   = lane >> 5;
    const int e0   = wv * 32;

    floatx16 acc = {};
#pragma unroll
    for (int kk = 0; kk < 16; ++kk) {
        half4 a  = *(const half4*)&Xs[ln * XW_PITCH + kk * 8 + hi * 4];
        half4 bf = *(const half4*)&Ws[(e0 + ln) * XW_PITCH + kk * 8 + hi * 4];
        acc = __builtin_amdgcn_mfma_f32_32x32x8f16(a, bf, acc, 0, 0, 0);
    }

    // D: col = e0+ln, row r_loc = (reg&3)+8*(reg>>2)+4*hi -> coalesced stores
#pragma unroll
    for (int reg = 0; reg < 16; ++reg) {
        const int r_loc = (reg & 3) + 8 * (reg >> 2) + 4 * hi;
        out[(size_t)(rbase + r_loc) * EMB + e0 + ln] = acc[reg];
    }
}

extern "C" void kernel_launch(void* const* d_in, const int* in_sizes, int n_in,
                              void* d_out, int out_size, void* d_ws, size_t ws_size,
                              hipStream_t stream) {
    const float* x     = (const float*)d_in[0];
    const float* theta = (const float*)d_in[1];
    const float* W     = (const float*)d_in[2];
    float*  out  = (float*)d_out;
    half_t* pD   = (half_t*)d_out;                            // Xn aliases out
    half_t* zrow = (half_t*)d_ws;                             // 1 MiB
    half_t* zT   = (half_t*)d_ws + (size_t)NBH * ZT_H_PER_BH; // 1 MiB @ +1 MiB

    zprep_kernel<<<NBH * 4, 512, 0, stream>>>(x, theta, zrow, zT);
    qattn_mfma_kernel<<<NBH * NQB, K1_THREADS, 0, stream>>>(zrow, zT, pD);
    combine_mfma_kernel<<<(NB * SEQ) / K2_ROWS, K2_THREADS, 0, stream>>>(pD, W, out);
}

// Round 18
// 28.492 us; speedup vs baseline: 1.0711x; 1.0711x over previous
//
#include <hip/hip_runtime.h>

#define SEQ   2048
#define EMB   128
#define NH    16
#define NB    2
#define NBH   (NB * NH)      // 32
#define QB    128            // q rows per block
#define NQB   (SEQ / QB)     // 16
#define SEQ_H 1024           // tokens staged per block (one t-half)
#define K1_THREADS 512

typedef _Float16 half_t;
typedef _Float16 half4  __attribute__((ext_vector_type(4)));
typedef __fp16   fp16x2 __attribute__((ext_vector_type(2)));  // cvt_pkrtz return type
typedef float    floatx16 __attribute__((ext_vector_type(16)));

// LDS carve (aliased, 36944 B total -> 4 blocks/CU by LDS):
//   zqk  : half4 [2][1024]              @ 0      (16384 B)  row-major z, K-frags
//   zT   : 10 rows x 2056 B             @ 16384  (20560 B)  transposed z, V-frags
//   red  : float[4352]                  @ 0      (alias, used after final sync)
#define SMEM_BYTES 36944
#define ZT_OFF     16384
#define ZT_PITCH   2056

// Kernel 1: MFMA flash attention partial. Block = (b,h,q-tile,t-half).
// Swapped QK^T (A=K, B=Q) so score regs feed the PV A-operand directly.
// V has a ones-column (d=8) so the row-sum l falls out of the same MFMA.
// QK MFMA is inline-asm with "=&v" D: R14's VGPR_Count=28 proved the
// compiler holds the score tile in AGPRs, so the 16 exp reads each paid a
// v_accvgpr_read (~32-40 cyc/iter on the binding VALU pipe). Forcing s
// into VGPRs deletes those. PV stays intrinsic (acc in AGPR is free --
// it is never read inside the loop). s_nop 7/7/1 covers the MFMA->VALU
// read hazard (R15-validated pattern).
__global__ __launch_bounds__(K1_THREADS, 4)
void qattn_mfma_kernel(const float* __restrict__ x,
                       const float* __restrict__ theta,
                       half_t* __restrict__ pD,
                       float* __restrict__ lbuf)
{
    __shared__ __align__(16) char smem[SMEM_BYTES];

    const int tid = threadIdx.x;
    const int bid = blockIdx.x;
    const int c2  = bid & 1;                 // t-half of the sequence
    const int qb  = (bid >> 1) & (NQB - 1);
    const int bh  = bid >> 5;                // 16 qb x 2 c2 blocks share (b,h)
    const int b   = bh >> 4;
    const int h   = bh & (NH - 1);

    float th[8];
#pragma unroll
    for (int d = 0; d < 8; ++d) th[d] = theta[d];

    const float4* x4 = (const float4*)x + (size_t)b * SEQ * (EMB / 4) + h * 2;

    half4* zqk0 = (half4*)smem;             // [t] = z[t][0..3]
    half4* zqk1 = (half4*)(smem + 8192);    // [t] = z[t][4..7]

    // ---- stage z = cos(x+theta) f16 for this t-half: row-major + transposed ----
#pragma unroll
    for (int i = 0; i < SEQ_H / K1_THREADS; ++i) {
        const int tl = tid + i * K1_THREADS;       // local token
        const int tg = c2 * SEQ_H + tl;            // global token
        float4 lo  = x4[(size_t)tg * (EMB / 4)];
        float4 hi4 = x4[(size_t)tg * (EMB / 4) + 1];
        float z0 = __cosf(lo.x  + th[0]);
        float z1 = __cosf(lo.y  + th[1]);
        float z2 = __cosf(lo.z  + th[2]);
        float z3 = __cosf(lo.w  + th[3]);
        float z4 = __cosf(hi4.x + th[4]);
        float z5 = __cosf(hi4.y + th[5]);
        float z6 = __cosf(hi4.z + th[6]);
        float z7 = __cosf(hi4.w + th[7]);
        half4 zl, zh;
        zl[0] = (half_t)z0; zl[1] = (half_t)z1; zl[2] = (half_t)z2; zl[3] = (half_t)z3;
        zh[0] = (half_t)z4; zh[1] = (half_t)z5; zh[2] = (half_t)z6; zh[3] = (half_t)z7;
        zqk0[tl] = zl;
        zqk1[tl] = zh;
#pragma unroll
        for (int d = 0; d < 4; ++d)
            *(half_t*)(smem + ZT_OFF + d * ZT_PITCH + tl * 2) = zl[d];
#pragma unroll
        for (int d = 0; d < 4; ++d)
            *(half_t*)(smem + ZT_OFF + (4 + d) * ZT_PITCH + tl * 2) = zh[d];
        *(half_t*)(smem + ZT_OFF + 8 * ZT_PITCH + tl * 2) = (half_t)1.0f;  // ones -> l
        *(half_t*)(smem + ZT_OFF + 9 * ZT_PITCH + tl * 2) = (half_t)0.0f;  // zero row
    }

    const int lane = tid & 63;
    const int wid  = tid >> 6;      // 0..7
    const int g    = wid & 3;       // q-tile (32 q) within block
    const int c    = wid >> 2;      // sub-half of this block's 1024 t
    const int ln   = lane & 31;
    const int hi   = lane >> 5;

    // Q from global (its token may live in the other t-half's staging).
    // exp(s/sqrt(8)) = exp2(s*C); fold C into Q (|C*z| <= 0.51, f16-safe)
    const float C = 0.35355339059327373f * 1.4426950408889634f;
    const int q = qb * QB + g * 32 + ln;
    float4 xq = ((const float4*)x)[(size_t)(b * SEQ + q) * (EMB / 4) + h * 2 + hi];
    half4 qf;
    qf[0] = (half_t)(__cosf(xq.x + th[4 * hi + 0]) * C);
    qf[1] = (half_t)(__cosf(xq.y + th[4 * hi + 1]) * C);
    qf[2] = (half_t)(__cosf(xq.z + th[4 * hi + 2]) * C);
    qf[3] = (half_t)(__cosf(xq.w + th[4 * hi + 3]) * C);

    __syncthreads();

    const half4* kp  = (hi ? zqk1 : zqk0) + ln;       // kp[t0] = z[t0+ln][4hi..]
    const int    dcl = (ln < 9) ? ln : 9;
    const half4* vp  = (const half4*)(smem + ZT_OFF + dcl * ZT_PITCH + hi * 8);

    floatx16 acc = {};
    const floatx16 zero16 = {};
    const int tb = c * (SEQ_H / 2);

#pragma unroll 1
    for (int tt = 0; tt < SEQ_H / 2; tt += 32) {
        const int t0 = tb + tt;
        half4 kf = kp[t0];
        // s[t_local, q]: q = ln, t_local = (r&3)+8*(r>>2)+4*hi (scaled scores).
        // Inline asm, same x8 shape as R10 (no operand marshalling), but D
        // pinned to VGPRs so the exps below read VGPRs directly.
        floatx16 s;
        asm volatile("v_mfma_f32_32x32x8_f16 %0, %1, %2, %3\n\t"
                     "s_nop 7\n\ts_nop 7\n\ts_nop 1"
                     : "=&v"(s)
                     : "v"(kf), "v"(qf), "v"(zero16));
        float p[16];
#pragma unroll
        for (int r = 0; r < 16; ++r) p[r] = __builtin_amdgcn_exp2f(s[r]);
#pragma unroll
        for (int w = 0; w < 4; ++w) {
            // PV A-frag for t-window w = regs 4w..4w+3
            union { half4 h4; fp16x2 f2[2]; } u;
            u.f2[0] = __builtin_amdgcn_cvt_pkrtz(p[4 * w + 0], p[4 * w + 1]);
            u.f2[1] = __builtin_amdgcn_cvt_pkrtz(p[4 * w + 2], p[4 * w + 3]);
            half4 vf = vp[(t0 >> 2) + 2 * w];
            acc = __builtin_amdgcn_mfma_f32_32x32x8f16(u.h4, vf, acc, 0, 0, 0);
        }
    }

    // ---- combine the 2 sub-halves (LDS alias), write unnormalized partials ----
    __syncthreads();                        // all zqk/zT reads done
    float* red = (float*)smem;
    const int slot = (g * 64 + lane) * 17;  // stride 17: conflict-free
    if (c == 1) {
#pragma unroll
        for (int r = 0; r < 16; ++r) red[slot + r] = acc[r];
    }
    __syncthreads();
    if (c == 0) {
#pragma unroll
        for (int r = 0; r < 16; ++r) acc[r] += red[slot + r];

        const int q0 = qb * QB + g * 32 + 4 * hi;
        if (ln < 8) {
#pragma unroll
            for (int r = 0; r < 16; ++r) {
                const int qq = q0 + (r & 3) + 8 * (r >> 2);
                pD[((size_t)(b * SEQ + qq) * 2 + c2) * EMB + h * 8 + ln] = (half_t)acc[r];
            }
        } else if (ln == 8) {
#pragma unroll
            for (int r = 0; r < 16; ++r) {
                const int qq = q0 + (r & 3) + 8 * (r >> 2);
                lbuf[(size_t)(b * SEQ + qq) * 32 + c2 * 16 + h] = acc[r];
            }
        }
    }
}

// Kernel 2 (MFMA): sum t-half partials, normalize -> Xn f16; W -> f16; then
// out[r][e] = sum_k Xn[r][k] W[e][k] via 32x32x8 f16 MFMA.
#define K2_ROWS    32
#define K2_THREADS 256
#define XW_PITCH   132

__global__ __launch_bounds__(K2_THREADS)
void combine_mfma_kernel(const half_t* pD,
                         const float* __restrict__ lbuf,
                         const float* __restrict__ W,
                         float* out)
{
    __shared__ half_t Ws[128 * XW_PITCH];      // [e][k] f16, 33792 B
    __shared__ half_t Xs[K2_ROWS * XW_PITCH];  // [r][k] f16 normalized, 8448 B

    const int tid   = threadIdx.x;
    const int rbase = blockIdx.x * K2_ROWS;

    // ---- stage W as f16 ----
#pragma unroll
    for (int it = 0; it < 16; ++it) {
        const int idx = tid + it * K2_THREADS;   // 0..4095 float4s
        const int e   = idx >> 5;
        const int k4  = idx & 31;
        float4 w = ((const float4*)W)[idx];
        union { half4 h4; fp16x2 f2[2]; } u;
        u.f2[0] = __builtin_amdgcn_cvt_pkrtz(w.x, w.y);
        u.f2[1] = __builtin_amdgcn_cvt_pkrtz(w.z, w.w);
        *(half4*)&Ws[e * XW_PITCH + 4 * k4] = u.h4;
    }
    // ---- stage Xn = (pD_half0 + pD_half1) / l as f16 ----
#pragma unroll
    for (int it = 0; it < 8; ++it) {
        const int idx = tid + it * K2_THREADS;   // 0..2047: (r, k2)
        const int r   = idx >> 6;
        const int k2  = idx & 63;                // k = 2*k2
        const int row = rbase + r;
        const half_t* p0 = &pD[(size_t)row * 256 + 2 * k2];
        const int hh = k2 >> 2;
        float l  = lbuf[(size_t)row * 32 + hh] + lbuf[(size_t)row * 32 + 16 + hh];
        float rl = __builtin_amdgcn_rcpf(l);
        float v0 = ((float)p0[0] + (float)p0[128]) * rl;
        float v1 = ((float)p0[1] + (float)p0[129]) * rl;
        *(fp16x2*)&Xs[r * XW_PITCH + 2 * k2] = __builtin_amdgcn_cvt_pkrtz(v0, v1);
    }
    __syncthreads();

    const int lane = tid & 63;
    const int wv   = tid >> 6;     // 0..3 -> e-tile
    const int ln   = lane & 31;
    const int hi   = lane >> 5;
    const int e0   = wv * 32;

    floatx16 acc = {};
#pragma unroll
    for (int kk = 0; kk < 16; ++kk) {
        half4 a  = *(const half4*)&Xs[ln * XW_PITCH + kk * 8 + hi * 4];         // X[r=ln][k..]
        half4 bf = *(const half4*)&Ws[(e0 + ln) * XW_PITCH + kk * 8 + hi * 4];  // W[e=ln][k..]
        acc = __builtin_amdgcn_mfma_f32_32x32x8f16(a, bf, acc, 0, 0, 0);
    }

    // D: col = e0+ln, row r_loc = (reg&3)+8*(reg>>2)+4*hi -> coalesced stores
#pragma unroll
    for (int reg = 0; reg < 16; ++reg) {
        const int r_loc = (reg & 3) + 8 * (reg >> 2) + 4 * hi;
        out[(size_t)(rbase + r_loc) * EMB + e0 + ln] = acc[reg];
    }
}

extern "C" void kernel_launch(void* const* d_in, const int* in_sizes, int n_in,
                              void* d_out, int out_size, void* d_ws, size_t ws_size,
                              hipStream_t stream) {
    const float* x     = (const float*)d_in[0];
    const float* theta = (const float*)d_in[1];
    const float* W     = (const float*)d_in[2];
    float*  out  = (float*)d_out;
    half_t* pD   = (half_t*)d_out;   // d_out doubles as f16 partial scratch
    float*  lbuf = (float*)d_ws;     // 512 KiB row-sum partials

    qattn_mfma_kernel<<<NBH * NQB * 2, K1_THREADS, 0, stream>>>(x, theta, pD, lbuf);
    combine_mfma_kernel<<<(NB * SEQ) / K2_ROWS, K2_THREADS, 0, stream>>>(pD, lbuf, W, out);
}